// Round 7
// baseline (173.975 us; speedup 1.0000x reference)
//
#include <hip/hip_runtime.h>
#include <hip/hip_bf16.h>
#include <math.h>

#define B_ 2
#define H_ 16
#define N_ 8192
#define D_ 64
#define R_ 7
#define BLOCK_ 256
#define SAMPLE_ 256
#define BH_ (B_*H_)
#define NBLK_ (N_/BLOCK_)

#define CHUNK_ 128           // keys staged per chunk
#define PADK 72              // Ks row stride: 144 B
#define PADV 132             // Vt row stride: 264 B

typedef __attribute__((ext_vector_type(8))) short bf16x8;
typedef __attribute__((ext_vector_type(4))) short bf16x4;
typedef __attribute__((ext_vector_type(4))) float f32x4;
typedef __attribute__((ext_vector_type(2))) unsigned int u32x2;
typedef __attribute__((ext_vector_type(4))) unsigned int u32x4;

__device__ inline unsigned short f2bf(float x) {
  __hip_bfloat16 h = __float2bfloat16(x);
  return *(unsigned short*)&h;
}
__device__ inline unsigned int pack2bf(float a, float b) {
  return (unsigned int)f2bf(a) | ((unsigned int)f2bf(b) << 16);
}
__device__ inline float fexp2(float x) {
#if __has_builtin(__builtin_amdgcn_exp2f)
  return __builtin_amdgcn_exp2f(x);
#else
  return exp2f(x);
#endif
}

// PV mfma: D = A(16x16: d x k) * B(16x16: k x q), K=16, bf16
__device__ inline f32x4 mfma16(bf16x4 a, bf16x4 b, f32x4 c) {
#if __has_builtin(__builtin_amdgcn_mfma_f32_16x16x16bf16_1k)
  return __builtin_amdgcn_mfma_f32_16x16x16bf16_1k(a, b, c, 0, 0, 0);
#else
  asm volatile("v_mfma_f32_16x16x16_bf16 %0, %1, %2, %0" : "+v"(c) : "v"(a), "v"(b));
  return c;
#endif
}

// ---------------- Kernel 1: LSH hash (UNCHANGED summation order — sign-flip safety) ----
__global__ __launch_bounds__(256) void hash_kernel(
    const float* __restrict__ q, const float* __restrict__ k,
    const float* __restrict__ pd, int* __restrict__ qh, int* __restrict__ kh) {
  __shared__ float spd[D_ * R_];
  for (int i = threadIdx.x; i < D_ * R_; i += blockDim.x) spd[i] = pd[i];
  __syncthreads();
  int tid = blockIdx.x * blockDim.x + threadIdx.x;
  const int half = BH_ * N_;
  const float* src = (tid < half) ? q : k;
  int* dst = (tid < half) ? qh : kh;
  int row = (tid < half) ? tid : tid - half;
  const float4* x4 = (const float4*)(src + (size_t)row * D_);
  float acc[R_];
#pragma unroll
  for (int r = 0; r < R_; r++) acc[r] = 0.f;
#pragma unroll
  for (int j = 0; j < 16; j++) {
    float4 v = x4[j];
#pragma unroll
    for (int r = 0; r < R_; r++) {
      acc[r] = fmaf(v.x, spd[(4 * j + 0) * R_ + r], acc[r]);
      acc[r] = fmaf(v.y, spd[(4 * j + 1) * R_ + r], acc[r]);
      acc[r] = fmaf(v.z, spd[(4 * j + 2) * R_ + r], acc[r]);
      acc[r] = fmaf(v.w, spd[(4 * j + 3) * R_ + r], acc[r]);
    }
  }
  int bin = 0;
#pragma unroll
  for (int r = 0; r < R_; r++) bin |= (acc[r] > 0.f) ? (1 << r) : 0;
  dst[row] = bin ^ (bin >> 1);
}

// ---------------- Kernel 2: stable counting sort per (b,h) ----------------
__global__ __launch_bounds__(64) void sort_kernel(
    const int* __restrict__ qh, const int* __restrict__ kh,
    int* __restrict__ qidx, int* __restrict__ kidx) {
  int g = blockIdx.x;
  int bh = g & (BH_ - 1);
  bool isK = g >= BH_;
  const int* h = (isK ? kh : qh) + (size_t)bh * N_;
  int* idx = (isK ? kidx : qidx) + (size_t)bh * N_;
  __shared__ int hist[128][64];
  __shared__ int tot[128];
  __shared__ int off[128];
  int t = threadIdx.x;
  for (int b = 0; b < 128; b++) hist[b][t] = 0;
  __syncthreads();
  const int base = t * 128;
  for (int j = 0; j < 128; j++) hist[h[base + j]][t]++;
  __syncthreads();
  for (int b = t; b < 128; b += 64) {
    int s = 0;
    for (int tt = 0; tt < 64; tt++) s += hist[b][tt];
    tot[b] = s;
  }
  __syncthreads();
  if (t == 0) {
    int run = 0;
    for (int b = 0; b < 128; b++) { off[b] = run; run += tot[b]; }
  }
  __syncthreads();
  for (int b = t; b < 128; b += 64) {
    int run = off[b];
    for (int tt = 0; tt < 64; tt++) { int tmp = hist[b][tt]; hist[b][tt] = run; run += tmp; }
  }
  __syncthreads();
  for (int j = 0; j < 128; j++) {
    int c = h[base + j];
    idx[hist[c][t]++] = base + j;
  }
}

// ---------------- Kernel 3: gather sampled K/V (256-thread blocks) ----------------
__global__ __launch_bounds__(256) void subgather_kernel(
    const float* __restrict__ key, const float* __restrict__ val,
    const int* __restrict__ kidx, const int* __restrict__ samp,
    float* __restrict__ ksub, float* __restrict__ vsub, int* __restrict__ sblk) {
  int sidx = blockIdx.x * 4 + (threadIdx.x >> 6);   // 0 .. BH*SAMPLE-1
  int bh = sidx >> 8;                                // SAMPLE_=256
  int d = threadIdx.x & 63;
  int pos = samp[sidx];
  int row = kidx[(size_t)bh * N_ + pos];
  ksub[(size_t)sidx * D_ + d] = key[((size_t)bh * N_ + row) * D_ + d];
  vsub[(size_t)sidx * D_ + d] = val[((size_t)bh * N_ + row) * D_ + d];
  if (d == 0) sblk[sidx] = pos >> 8;                 // BLOCK_=256
}

// ---------------- Kernel 4: MFMA fused attention, T14 async staging ----------------
// grid = BH*NBLK, 512 threads (8 waves). Wave w owns queries [w*32, w*32+32).
// T14 split: chunk c+1's global loads ISSUE before phase(c) (latency hides under
// MFMA+exp compute); after the post-phase barrier only cvt+ds_write runs (short).
// No global-latency segment sits between any barrier pair.
// QK: S^T = K x Q^T mfma_16x16x32, scale*log2e folded into Q. PV: O^T = V^T x W
// mfma_16x16x16 + ones-fragment accumulator for ls on the MFMA pipe.
__global__ __launch_bounds__(512, 4) void attn_kernel(
    const float* __restrict__ query, const float* __restrict__ key,
    const float* __restrict__ value,
    const int* __restrict__ qidx, const int* __restrict__ kidx,
    const float* __restrict__ ksub, const float* __restrict__ vsub,
    const int* __restrict__ sblk, float* __restrict__ out) {
  __shared__ __align__(16) unsigned short KsL[CHUNK_ * PADK];   // 18432 B
  __shared__ __align__(16) unsigned short VtL[D_ * PADV];       // 16896 B
  __shared__ int sbs[CHUNK_];

  const int bh = blockIdx.x / NBLK_;
  const int blk = blockIdx.x - bh * NBLK_;
  const int tid = threadIdx.x;
  const int w = tid >> 6;       // wave 0..7
  const int lane = tid & 63;
  const int lg = lane >> 4;
  const int lr = lane & 15;
  const float FOLD = 0.18033688011112042f;   // (1/8) * log2(e)
  const int kp = tid >> 3, dq = tid & 7;     // staging: (k-pair, d-octant)

  // ---- staged-register chunk (raw f32; cvt happens in the write segment) ----
  float4 sk0a, sk0b, sk1a, sk1b, sv0a, sv0b, sv1a, sv1b;
  int sreg = 0;

  auto load_block = [&](int c) {
    size_t ib = (size_t)bh * N_ + blk * BLOCK_ + c * CHUNK_ + 2 * kp;
    int r0 = kidx[ib], r1 = kidx[ib + 1];
    const float* k0 = key + ((size_t)bh * N_ + r0) * D_ + dq * 8;
    const float* k1 = key + ((size_t)bh * N_ + r1) * D_ + dq * 8;
    const float* v0 = value + ((size_t)bh * N_ + r0) * D_ + dq * 8;
    const float* v1 = value + ((size_t)bh * N_ + r1) * D_ + dq * 8;
    sk0a = *(const float4*)k0; sk0b = *(const float4*)(k0 + 4);
    sk1a = *(const float4*)k1; sk1b = *(const float4*)(k1 + 4);
    sv0a = *(const float4*)v0; sv0b = *(const float4*)(v0 + 4);
    sv1a = *(const float4*)v1; sv1b = *(const float4*)(v1 + 4);
  };
  auto load_sample = [&](int c) {
    size_t b0 = ((size_t)bh * SAMPLE_ + c * CHUNK_ + 2 * kp) * D_ + dq * 8;
    sk0a = *(const float4*)(ksub + b0);      sk0b = *(const float4*)(ksub + b0 + 4);
    sk1a = *(const float4*)(ksub + b0 + D_); sk1b = *(const float4*)(ksub + b0 + D_ + 4);
    sv0a = *(const float4*)(vsub + b0);      sv0b = *(const float4*)(vsub + b0 + 4);
    sv1a = *(const float4*)(vsub + b0 + D_); sv1b = *(const float4*)(vsub + b0 + D_ + 4);
    if (tid < CHUNK_) sreg = sblk[(size_t)bh * SAMPLE_ + c * CHUNK_ + tid];
  };
  auto write_kv = [&](bool issb) {
    u32x4 pk0 = (u32x4){pack2bf(sk0a.x, sk0a.y), pack2bf(sk0a.z, sk0a.w),
                        pack2bf(sk0b.x, sk0b.y), pack2bf(sk0b.z, sk0b.w)};
    u32x4 pk1 = (u32x4){pack2bf(sk1a.x, sk1a.y), pack2bf(sk1a.z, sk1a.w),
                        pack2bf(sk1b.x, sk1b.y), pack2bf(sk1b.z, sk1b.w)};
    *(u32x4*)&KsL[(2 * kp + 0) * PADK + dq * 8] = pk0;
    *(u32x4*)&KsL[(2 * kp + 1) * PADK + dq * 8] = pk1;
    float a0[8] = {sv0a.x, sv0a.y, sv0a.z, sv0a.w, sv0b.x, sv0b.y, sv0b.z, sv0b.w};
    float a1[8] = {sv1a.x, sv1a.y, sv1a.z, sv1a.w, sv1b.x, sv1b.y, sv1b.z, sv1b.w};
#pragma unroll
    for (int j = 0; j < 8; j++)
      *(unsigned*)&VtL[(dq * 8 + j) * PADV + 2 * kp] = pack2bf(a0[j], a1[j]);
    if (issb && tid < CHUNK_) sbs[tid] = sreg;
  };

  // ---- prologue: issue chunk-0 + own-Q loads, then convert/write, barrier ----
  load_block(0);
  int qrw[2];
  qrw[0] = qidx[(size_t)bh * N_ + blk * BLOCK_ + w * 32 + lr];
  qrw[1] = qidx[(size_t)bh * N_ + blk * BLOCK_ + w * 32 + 16 + lr];
  float4 qraw[2][4];
#pragma unroll
  for (int qt = 0; qt < 2; qt++) {
    const float* qp = query + ((size_t)bh * N_ + qrw[qt]) * D_ + lg * 8;
    qraw[qt][0] = *(const float4*)(qp);
    qraw[qt][1] = *(const float4*)(qp + 4);
    qraw[qt][2] = *(const float4*)(qp + 32);
    qraw[qt][3] = *(const float4*)(qp + 36);
  }
  write_kv(false);
  bf16x8 qf[2][2];
#pragma unroll
  for (int qt = 0; qt < 2; qt++) {
#pragma unroll
    for (int h = 0; h < 2; h++) {
      float4 a = qraw[qt][2 * h], b = qraw[qt][2 * h + 1];
      union { u32x4 u; bf16x8 v; } cv;
      cv.u = (u32x4){pack2bf(a.x * FOLD, a.y * FOLD), pack2bf(a.z * FOLD, a.w * FOLD),
                     pack2bf(b.x * FOLD, b.y * FOLD), pack2bf(b.z * FOLD, b.w * FOLD)};
      qf[qt][h] = cv.v;
    }
  }
  __syncthreads();

  // ---- ones A-fragment: A[row 0][*] = 1 -> D row 0 = column sums of W ----
  const bf16x4 avONE = (lr == 0)
      ? (bf16x4){(short)0x3F80, (short)0x3F80, (short)0x3F80, (short)0x3F80}
      : (bf16x4){0, 0, 0, 0};

  f32x4 oA[2][5], oB[2][5];   // [qt][dt]; dt==4 is the ls accumulator
#pragma unroll
  for (int a = 0; a < 2; a++)
#pragma unroll
    for (int b = 0; b < 5; b++) { oA[a][b] = (f32x4){0.f,0.f,0.f,0.f}; oB[a][b] = (f32x4){0.f,0.f,0.f,0.f}; }

  auto phase = [&](f32x4 (&o)[2][5], bool masked) {
#pragma unroll 1
    for (int kt = 0; kt < 8; kt++) {
      const unsigned short* krow = &KsL[(kt * 16 + lr) * PADK + lg * 8];
      bf16x8 ak0 = *(const bf16x8*)(krow);
      bf16x8 ak1 = *(const bf16x8*)(krow + 32);
      bf16x4 av[4];
#pragma unroll
      for (int dt = 0; dt < 4; dt++)
        av[dt] = *(const bf16x4*)(&VtL[(dt * 16 + lr) * PADV + kt * 16 + lg * 4]);
      float msk[4];
      if (masked) {
#pragma unroll
        for (int r = 0; r < 4; r++)
          msk[r] = (sbs[kt * 16 + lg * 4 + r] == blk) ? 0.f : 1.f;
      }
      bf16x4 bq[2];
#pragma unroll
      for (int qt = 0; qt < 2; qt++) {
        f32x4 c = (f32x4){0.f, 0.f, 0.f, 0.f};
        c = __builtin_amdgcn_mfma_f32_16x16x32_bf16(ak0, qf[qt][0], c, 0, 0, 0);
        c = __builtin_amdgcn_mfma_f32_16x16x32_bf16(ak1, qf[qt][1], c, 0, 0, 0);
        float w0 = fexp2(c[0]), w1 = fexp2(c[1]);
        float w2 = fexp2(c[2]), w3 = fexp2(c[3]);
        if (masked) { w0 *= msk[0]; w1 *= msk[1]; w2 *= msk[2]; w3 *= msk[3]; }
        union { u32x2 u; bf16x4 v; } cv;
        cv.u = (u32x2){pack2bf(w0, w1), pack2bf(w2, w3)};
        bq[qt] = cv.v;
      }
#pragma unroll
      for (int qt = 0; qt < 2; qt++) {
#pragma unroll
        for (int dt = 0; dt < 4; dt++)
          o[qt][dt] = mfma16(av[dt], bq[qt], o[qt][dt]);
        o[qt][4] = mfma16(avONE, bq[qt], o[qt][4]);
      }
    }
  };

  // ---- pipelined chunks: block0, block1, sample0, sample1 ----
  load_block(1);          // prefetch under phase(block0)
  phase(oA, false);
  __syncthreads();
  write_kv(false);
  __syncthreads();

  load_sample(0);         // prefetch under phase(block1)
  phase(oA, false);
  __syncthreads();
  write_kv(true);
  __syncthreads();

  load_sample(1);         // prefetch under phase(sample0)
  phase(oB, true);
  __syncthreads();
  write_kv(true);
  __syncthreads();

  phase(oB, true);

  // ---- merge + scatter (lane owns q = qt*16+lr, d = dt*16+lg*4..+4) ----
#pragma unroll
  for (int qt = 0; qt < 2; qt++) {
    float lb = __shfl(oA[qt][4][0], lr);     // lane (lr, lg=0) holds sum for q=lr
    float lrv = __shfl(oB[qt][4][0], lr);
    float wb, wr;
    float lseb = __logf(lb);
    if (lrv > 0.f) {
      float lser = __logf(lrv) + 3.4657359027997265f;  // + log(32)
      float cc = 1.f / (1.f + __expf(lser - lseb));
      wb = cc / lb; wr = (1.f - cc) / lrv;
    } else {
      wb = 1.f / lb; wr = 0.f;
    }
    float* op = out + ((size_t)bh * N_ + qrw[qt]) * D_ + lg * 4;
#pragma unroll
    for (int dt = 0; dt < 4; dt++) {
      float4 o;
      o.x = wb * oA[qt][dt][0] + wr * oB[qt][dt][0];
      o.y = wb * oA[qt][dt][1] + wr * oB[qt][dt][1];
      o.z = wb * oA[qt][dt][2] + wr * oB[qt][dt][2];
      o.w = wb * oA[qt][dt][3] + wr * oB[qt][dt][3];
      *(float4*)(op + dt * 16) = o;
    }
  }
}

extern "C" void kernel_launch(void* const* d_in, const int* in_sizes, int n_in,
                              void* d_out, int out_size, void* d_ws, size_t ws_size,
                              hipStream_t stream) {
  const float* query = (const float*)d_in[0];
  const float* key   = (const float*)d_in[1];
  const float* value = (const float*)d_in[2];
  const float* pd    = (const float*)d_in[3];
  const int*   samp  = (const int*)d_in[4];
  float* out = (float*)d_out;

  char* w = (char*)d_ws;
  size_t o = 0;
  auto alloc = [&](size_t bytes) { void* p = w + o; o = (o + bytes + 255) & ~(size_t)255; return p; };
  int* qh   = (int*)alloc((size_t)BH_ * N_ * 4);
  int* kh   = (int*)alloc((size_t)BH_ * N_ * 4);
  int* qidx = (int*)alloc((size_t)BH_ * N_ * 4);
  int* kidx = (int*)alloc((size_t)BH_ * N_ * 4);
  float* ksub = (float*)alloc((size_t)BH_ * SAMPLE_ * D_ * 4);
  float* vsub = (float*)alloc((size_t)BH_ * SAMPLE_ * D_ * 4);
  int* sblk = (int*)alloc((size_t)BH_ * SAMPLE_ * 4);

  hash_kernel<<<(2 * BH_ * N_) / 256, 256, 0, stream>>>(query, key, pd, qh, kh);
  sort_kernel<<<2 * BH_, 64, 0, stream>>>(qh, kh, qidx, kidx);
  subgather_kernel<<<BH_ * SAMPLE_ / 4, 256, 0, stream>>>(key, value, kidx, samp, ksub, vsub, sblk);
  attn_kernel<<<BH_ * NBLK_, 512, 0, stream>>>(query, key, value, qidx, kidx,
                                               ksub, vsub, sblk, out);
}

// Round 8
// 161.618 us; speedup vs baseline: 1.0765x; 1.0765x over previous
//
#include <hip/hip_runtime.h>
#include <hip/hip_bf16.h>
#include <math.h>

#define B_ 2
#define H_ 16
#define N_ 8192
#define D_ 64
#define R_ 7
#define BLOCK_ 256
#define SAMPLE_ 256
#define BH_ (B_*H_)
#define NBLK_ (N_/BLOCK_)

#define CHUNK_ 128           // keys staged per chunk
#define PADK 72              // Ks row stride: 144 B
#define PADV 132             // Vt row stride: 264 B
#define IMGK_BYTES (CHUNK_*PADK*2)          // 18432 B  (byte image of KsL)
#define IMGV_BYTES (D_*PADV*2)              // 16896 B  (byte image of VtL)
#define IMG_STRIDE (IMGK_BYTES+IMGV_BYTES)  // 35328 B per (bh,chunk)

typedef __attribute__((ext_vector_type(8))) short bf16x8;
typedef __attribute__((ext_vector_type(4))) short bf16x4;
typedef __attribute__((ext_vector_type(4))) float f32x4;
typedef __attribute__((ext_vector_type(2))) unsigned int u32x2;
typedef __attribute__((ext_vector_type(4))) unsigned int u32x4;

__device__ inline unsigned short f2bf(float x) {
  __hip_bfloat16 h = __float2bfloat16(x);
  return *(unsigned short*)&h;
}
__device__ inline unsigned int pack2bf(float a, float b) {
  return (unsigned int)f2bf(a) | ((unsigned int)f2bf(b) << 16);
}
__device__ inline float fexp2(float x) {
#if __has_builtin(__builtin_amdgcn_exp2f)
  return __builtin_amdgcn_exp2f(x);
#else
  return exp2f(x);
#endif
}

// PV mfma: D = A(16x16: d x k) * B(16x16: k x q), K=16, bf16
__device__ inline f32x4 mfma16(bf16x4 a, bf16x4 b, f32x4 c) {
#if __has_builtin(__builtin_amdgcn_mfma_f32_16x16x16bf16_1k)
  return __builtin_amdgcn_mfma_f32_16x16x16bf16_1k(a, b, c, 0, 0, 0);
#else
  asm volatile("v_mfma_f32_16x16x16_bf16 %0, %1, %2, %0" : "+v"(c) : "v"(a), "v"(b));
  return c;
#endif
}

// ---------------- Kernel 1: LSH hash (UNCHANGED summation order — sign-flip safety) ----
__global__ __launch_bounds__(256) void hash_kernel(
    const float* __restrict__ q, const float* __restrict__ k,
    const float* __restrict__ pd, int* __restrict__ qh, int* __restrict__ kh) {
  __shared__ float spd[D_ * R_];
  for (int i = threadIdx.x; i < D_ * R_; i += blockDim.x) spd[i] = pd[i];
  __syncthreads();
  int tid = blockIdx.x * blockDim.x + threadIdx.x;
  const int half = BH_ * N_;
  const float* src = (tid < half) ? q : k;
  int* dst = (tid < half) ? qh : kh;
  int row = (tid < half) ? tid : tid - half;
  const float4* x4 = (const float4*)(src + (size_t)row * D_);
  float acc[R_];
#pragma unroll
  for (int r = 0; r < R_; r++) acc[r] = 0.f;
#pragma unroll
  for (int j = 0; j < 16; j++) {
    float4 v = x4[j];
#pragma unroll
    for (int r = 0; r < R_; r++) {
      acc[r] = fmaf(v.x, spd[(4 * j + 0) * R_ + r], acc[r]);
      acc[r] = fmaf(v.y, spd[(4 * j + 1) * R_ + r], acc[r]);
      acc[r] = fmaf(v.z, spd[(4 * j + 2) * R_ + r], acc[r]);
      acc[r] = fmaf(v.w, spd[(4 * j + 3) * R_ + r], acc[r]);
    }
  }
  int bin = 0;
#pragma unroll
  for (int r = 0; r < R_; r++) bin |= (acc[r] > 0.f) ? (1 << r) : 0;
  dst[row] = bin ^ (bin >> 1);
}

// ---------------- Kernel 2: stable counting sort per (b,h) ----------------
__global__ __launch_bounds__(64) void sort_kernel(
    const int* __restrict__ qh, const int* __restrict__ kh,
    int* __restrict__ qidx, int* __restrict__ kidx) {
  int g = blockIdx.x;
  int bh = g & (BH_ - 1);
  bool isK = g >= BH_;
  const int* h = (isK ? kh : qh) + (size_t)bh * N_;
  int* idx = (isK ? kidx : qidx) + (size_t)bh * N_;
  __shared__ int hist[128][64];
  __shared__ int tot[128];
  __shared__ int off[128];
  int t = threadIdx.x;
  for (int b = 0; b < 128; b++) hist[b][t] = 0;
  __syncthreads();
  const int base = t * 128;
  for (int j = 0; j < 128; j++) hist[h[base + j]][t]++;
  __syncthreads();
  for (int b = t; b < 128; b += 64) {
    int s = 0;
    for (int tt = 0; tt < 64; tt++) s += hist[b][tt];
    tot[b] = s;
  }
  __syncthreads();
  if (t == 0) {
    int run = 0;
    for (int b = 0; b < 128; b++) { off[b] = run; run += tot[b]; }
  }
  __syncthreads();
  for (int b = t; b < 128; b += 64) {
    int run = off[b];
    for (int tt = 0; tt < 64; tt++) { int tmp = hist[b][tt]; hist[b][tt] = run; run += tmp; }
  }
  __syncthreads();
  for (int j = 0; j < 128; j++) {
    int c = h[base + j];
    idx[hist[c][t]++] = base + j;
  }
}

// ---------------- Kernel 3: sampled K/V -> bf16 LDS-image (padded/transposed) -------
// grid = BH*SAMPLE/4 blocks x 256 thr; thread = (sample-in-block, d).
// Writes the EXACT byte image of attn's KsL/VtL so attn stages samples with a
// linear vector copy (no gather chain, no cvt, no scatter conflicts).
__global__ __launch_bounds__(256) void sample_image_kernel(
    const float* __restrict__ key, const float* __restrict__ val,
    const int* __restrict__ kidx, const int* __restrict__ samp,
    unsigned short* __restrict__ img, int* __restrict__ sblk) {
  int s = blockIdx.x * 4 + (threadIdx.x >> 6);   // 0 .. BH*SAMPLE-1
  int bh = s >> 8;                                // SAMPLE_=256
  int d = threadIdx.x & 63;
  int pos = samp[s];
  int row = kidx[(size_t)bh * N_ + pos];
  int kk = s & 255;
  int c = kk >> 7, kkc = kk & 127;
  unsigned short* base = img + ((size_t)(bh * 2 + c) * IMG_STRIDE) / 2;
  float kf = key[((size_t)bh * N_ + row) * D_ + d];
  float vf = val[((size_t)bh * N_ + row) * D_ + d];
  base[kkc * PADK + d] = f2bf(kf);                       // K image (row-major, padded)
  base[IMGK_BYTES / 2 + d * PADV + kkc] = f2bf(vf);      // V^T image
  if (d == 0) sblk[s] = pos >> 8;                        // BLOCK_=256
}

// ---------------- Kernel 4: MFMA fused attention ----------------
// grid = BH*NBLK, 512 threads (8 waves). Wave w owns queries [w*32, w*32+32).
// R6 structure (in-segment staging; NO cross-phase register staging — R7 spill
// lesson). Latency removed from segments instead:
//  - sample segments: linear u32x4 copy of pre-built bf16 images (L2-hot)
//  - block chunk 1: kidx pair prefetched at prologue (one round trip, not two)
//  - sblk prefetched at prologue (2 regs)
__global__ __launch_bounds__(512, 4) void attn_kernel(
    const float* __restrict__ query, const float* __restrict__ key,
    const float* __restrict__ value,
    const int* __restrict__ qidx, const int* __restrict__ kidx,
    const unsigned short* __restrict__ img,
    const int* __restrict__ sblk, float* __restrict__ out) {
  __shared__ __align__(16) unsigned short KsL[CHUNK_ * PADK];   // 18432 B
  __shared__ __align__(16) unsigned short VtL[D_ * PADV];       // 16896 B
  __shared__ int sbs[CHUNK_];

  const int bh = blockIdx.x / NBLK_;
  const int blk = blockIdx.x - bh * NBLK_;
  const int tid = threadIdx.x;
  const int w = tid >> 6;       // wave 0..7
  const int lane = tid & 63;
  const int lg = lane >> 4;
  const int lr = lane & 15;
  const float FOLD = 0.18033688011112042f;   // (1/8) * log2(e)
  const int kp = tid >> 3, dq = tid & 7;     // staging: (k-pair, d-octant)

  // ---- prologue prefetches (4 VGPRs of cross-phase state, no spill) ----
  size_t ib1 = (size_t)bh * N_ + blk * BLOCK_ + CHUNK_ + 2 * kp;
  int r0p = kidx[ib1], r1p = kidx[ib1 + 1];            // chunk-1 rows
  int sreg0 = 0, sreg1 = 0;
  if (tid < CHUNK_) {
    sreg0 = sblk[(size_t)bh * SAMPLE_ + tid];
    sreg1 = sblk[(size_t)bh * SAMPLE_ + CHUNK_ + tid];
  }

  // ---- in-segment staging of a gathered block chunk (R6 code) ----
  auto stage_rows = [&](int r0, int r1) {
    const float* k0 = key + ((size_t)bh * N_ + r0) * D_ + dq * 8;
    const float* k1 = key + ((size_t)bh * N_ + r1) * D_ + dq * 8;
    const float* v0 = value + ((size_t)bh * N_ + r0) * D_ + dq * 8;
    const float* v1 = value + ((size_t)bh * N_ + r1) * D_ + dq * 8;
    float4 ka0 = *(const float4*)(k0), ka1 = *(const float4*)(k0 + 4);
    float4 kb0 = *(const float4*)(k1), kb1 = *(const float4*)(k1 + 4);
    u32x4 pk0 = (u32x4){pack2bf(ka0.x, ka0.y), pack2bf(ka0.z, ka0.w),
                        pack2bf(ka1.x, ka1.y), pack2bf(ka1.z, ka1.w)};
    u32x4 pk1 = (u32x4){pack2bf(kb0.x, kb0.y), pack2bf(kb0.z, kb0.w),
                        pack2bf(kb1.x, kb1.y), pack2bf(kb1.z, kb1.w)};
    *(u32x4*)&KsL[(2 * kp + 0) * PADK + dq * 8] = pk0;
    *(u32x4*)&KsL[(2 * kp + 1) * PADK + dq * 8] = pk1;
    float4 va0 = *(const float4*)(v0), va1 = *(const float4*)(v0 + 4);
    float4 vb0 = *(const float4*)(v1), vb1 = *(const float4*)(v1 + 4);
    float a0[8] = {va0.x, va0.y, va0.z, va0.w, va1.x, va1.y, va1.z, va1.w};
    float a1[8] = {vb0.x, vb0.y, vb0.z, vb0.w, vb1.x, vb1.y, vb1.z, vb1.w};
#pragma unroll
    for (int j = 0; j < 8; j++)
      *(unsigned*)&VtL[(dq * 8 + j) * PADV + 2 * kp] = pack2bf(a0[j], a1[j]);
  };

  // ---- linear image copy for sample chunks (no gather, no cvt) ----
  auto copy_image = [&](int c) {
    const unsigned short* ib = img + ((size_t)(bh * 2 + c) * IMG_STRIDE) / 2;
    const u32x4* srcK = (const u32x4*)ib;
    u32x4* dstK = (u32x4*)KsL;
    for (int i = tid; i < IMGK_BYTES / 16; i += 512) dstK[i] = srcK[i];
    const u32x4* srcV = (const u32x4*)(ib + IMGK_BYTES / 2);
    u32x4* dstV = (u32x4*)VtL;
    for (int i = tid; i < IMGV_BYTES / 16; i += 512) dstV[i] = srcV[i];
  };

  // ---- prologue: chunk 0 + own-Q ----
  {
    size_t ib0 = (size_t)bh * N_ + blk * BLOCK_ + 2 * kp;
    stage_rows(kidx[ib0], kidx[ib0 + 1]);
  }
  int qrw[2];
  qrw[0] = qidx[(size_t)bh * N_ + blk * BLOCK_ + w * 32 + lr];
  qrw[1] = qidx[(size_t)bh * N_ + blk * BLOCK_ + w * 32 + 16 + lr];
  bf16x8 qf[2][2];
#pragma unroll
  for (int qt = 0; qt < 2; qt++) {
    const float* qp = query + ((size_t)bh * N_ + qrw[qt]) * D_ + lg * 8;
#pragma unroll
    for (int h = 0; h < 2; h++) {
      float4 a = *(const float4*)(qp + h * 32);
      float4 b = *(const float4*)(qp + h * 32 + 4);
      union { u32x4 u; bf16x8 v; } cv;
      cv.u = (u32x4){pack2bf(a.x * FOLD, a.y * FOLD), pack2bf(a.z * FOLD, a.w * FOLD),
                     pack2bf(b.x * FOLD, b.y * FOLD), pack2bf(b.z * FOLD, b.w * FOLD)};
      qf[qt][h] = cv.v;
    }
  }
  __syncthreads();

  // ---- ones A-fragment: A[row 0][*] = 1 -> D row 0 = column sums of W ----
  const bf16x4 avONE = (lr == 0)
      ? (bf16x4){(short)0x3F80, (short)0x3F80, (short)0x3F80, (short)0x3F80}
      : (bf16x4){0, 0, 0, 0};

  f32x4 oA[2][5], oB[2][5];   // [qt][dt]; dt==4 is the ls accumulator
#pragma unroll
  for (int a = 0; a < 2; a++)
#pragma unroll
    for (int b = 0; b < 5; b++) { oA[a][b] = (f32x4){0.f,0.f,0.f,0.f}; oB[a][b] = (f32x4){0.f,0.f,0.f,0.f}; }

  auto phase = [&](f32x4 (&o)[2][5], bool masked) {
#pragma unroll 1
    for (int kt = 0; kt < 8; kt++) {
      const unsigned short* krow = &KsL[(kt * 16 + lr) * PADK + lg * 8];
      bf16x8 ak0 = *(const bf16x8*)(krow);
      bf16x8 ak1 = *(const bf16x8*)(krow + 32);
      bf16x4 av[4];
#pragma unroll
      for (int dt = 0; dt < 4; dt++)
        av[dt] = *(const bf16x4*)(&VtL[(dt * 16 + lr) * PADV + kt * 16 + lg * 4]);
      float msk[4];
      if (masked) {
#pragma unroll
        for (int r = 0; r < 4; r++)
          msk[r] = (sbs[kt * 16 + lg * 4 + r] == blk) ? 0.f : 1.f;
      }
      bf16x4 bq[2];
#pragma unroll
      for (int qt = 0; qt < 2; qt++) {
        f32x4 c = (f32x4){0.f, 0.f, 0.f, 0.f};
        c = __builtin_amdgcn_mfma_f32_16x16x32_bf16(ak0, qf[qt][0], c, 0, 0, 0);
        c = __builtin_amdgcn_mfma_f32_16x16x32_bf16(ak1, qf[qt][1], c, 0, 0, 0);
        float w0 = fexp2(c[0]), w1 = fexp2(c[1]);
        float w2 = fexp2(c[2]), w3 = fexp2(c[3]);
        if (masked) { w0 *= msk[0]; w1 *= msk[1]; w2 *= msk[2]; w3 *= msk[3]; }
        union { u32x2 u; bf16x4 v; } cv;
        cv.u = (u32x2){pack2bf(w0, w1), pack2bf(w2, w3)};
        bq[qt] = cv.v;
      }
#pragma unroll
      for (int qt = 0; qt < 2; qt++) {
#pragma unroll
        for (int dt = 0; dt < 4; dt++)
          o[qt][dt] = mfma16(av[dt], bq[qt], o[qt][dt]);
        o[qt][4] = mfma16(avONE, bq[qt], o[qt][4]);
      }
    }
  };

  // ---- chunks: block0, block1, sample0, sample1 ----
  phase(oA, false);
  __syncthreads();
  stage_rows(r0p, r1p);                 // chunk 1 (prefetched indices: 1 round trip)
  __syncthreads();
  phase(oA, false);
  __syncthreads();

  copy_image(0);                        // sample chunk 0 (linear, L2-hot)
  if (tid < CHUNK_) sbs[tid] = sreg0;
  __syncthreads();
  phase(oB, true);
  __syncthreads();
  copy_image(1);                        // sample chunk 1
  if (tid < CHUNK_) sbs[tid] = sreg1;
  __syncthreads();
  phase(oB, true);

  // ---- merge + scatter (lane owns q = qt*16+lr, d = dt*16+lg*4..+4) ----
#pragma unroll
  for (int qt = 0; qt < 2; qt++) {
    float lb = __shfl(oA[qt][4][0], lr);     // lane (lr, lg=0) holds sum for q=lr
    float lrv = __shfl(oB[qt][4][0], lr);
    float wb, wr;
    float lseb = __logf(lb);
    if (lrv > 0.f) {
      float lser = __logf(lrv) + 3.4657359027997265f;  // + log(32)
      float cc = 1.f / (1.f + __expf(lser - lseb));
      wb = cc / lb; wr = (1.f - cc) / lrv;
    } else {
      wb = 1.f / lb; wr = 0.f;
    }
    float* op = out + ((size_t)bh * N_ + qrw[qt]) * D_ + lg * 4;
#pragma unroll
    for (int dt = 0; dt < 4; dt++) {
      float4 o;
      o.x = wb * oA[qt][dt][0] + wr * oB[qt][dt][0];
      o.y = wb * oA[qt][dt][1] + wr * oB[qt][dt][1];
      o.z = wb * oA[qt][dt][2] + wr * oB[qt][dt][2];
      o.w = wb * oA[qt][dt][3] + wr * oB[qt][dt][3];
      *(float4*)(op + dt * 16) = o;
    }
  }
}

extern "C" void kernel_launch(void* const* d_in, const int* in_sizes, int n_in,
                              void* d_out, int out_size, void* d_ws, size_t ws_size,
                              hipStream_t stream) {
  const float* query = (const float*)d_in[0];
  const float* key   = (const float*)d_in[1];
  const float* value = (const float*)d_in[2];
  const float* pd    = (const float*)d_in[3];
  const int*   samp  = (const int*)d_in[4];
  float* out = (float*)d_out;

  char* w = (char*)d_ws;
  size_t o = 0;
  auto alloc = [&](size_t bytes) { void* p = w + o; o = (o + bytes + 255) & ~(size_t)255; return p; };
  int* qh   = (int*)alloc((size_t)BH_ * N_ * 4);
  int* kh   = (int*)alloc((size_t)BH_ * N_ * 4);
  int* qidx = (int*)alloc((size_t)BH_ * N_ * 4);
  int* kidx = (int*)alloc((size_t)BH_ * N_ * 4);
  unsigned short* img = (unsigned short*)alloc((size_t)BH_ * 2 * IMG_STRIDE);
  int* sblk = (int*)alloc((size_t)BH_ * SAMPLE_ * 4);

  hash_kernel<<<(2 * BH_ * N_) / 256, 256, 0, stream>>>(query, key, pd, qh, kh);
  sort_kernel<<<2 * BH_, 64, 0, stream>>>(qh, kh, qidx, kidx);
  sample_image_kernel<<<BH_ * SAMPLE_ / 4, 256, 0, stream>>>(key, value, kidx, samp, img, sblk);
  attn_kernel<<<BH_ * NBLK_, 512, 0, stream>>>(query, key, value, qidx, kidx,
                                               img, sblk, out);
}

// Round 10
// 118.919 us; speedup vs baseline: 1.4630x; 1.3591x over previous
//
#include <hip/hip_runtime.h>
#include <hip/hip_bf16.h>
#include <math.h>

#define B_ 2
#define H_ 16
#define N_ 8192
#define D_ 64
#define R_ 7
#define BLOCK_ 256
#define SAMPLE_ 256
#define BH_ (B_*H_)
#define NBLK_ (N_/BLOCK_)

#define CHUNK_ 128           // keys staged per chunk
#define PADK 72              // Ks row stride: 144 B
#define PADV 132             // Vt row stride: 264 B

typedef __attribute__((ext_vector_type(8))) short bf16x8;
typedef __attribute__((ext_vector_type(4))) short bf16x4;
typedef __attribute__((ext_vector_type(4))) float f32x4;
typedef __attribute__((ext_vector_type(2))) unsigned int u32x2;
typedef __attribute__((ext_vector_type(4))) unsigned int u32x4;

__device__ inline unsigned short f2bf(float x) {
  __hip_bfloat16 h = __float2bfloat16(x);
  return *(unsigned short*)&h;
}
__device__ inline unsigned int pack2bf(float a, float b) {
  return (unsigned int)f2bf(a) | ((unsigned int)f2bf(b) << 16);
}
__device__ inline float fexp2(float x) {
#if __has_builtin(__builtin_amdgcn_exp2f)
  return __builtin_amdgcn_exp2f(x);
#else
  return exp2f(x);
#endif
}

// PV mfma: D = A(16x16: d x k) * B(16x16: k x q), K=16, bf16
__device__ inline f32x4 mfma16(bf16x4 a, bf16x4 b, f32x4 c) {
#if __has_builtin(__builtin_amdgcn_mfma_f32_16x16x16bf16_1k)
  return __builtin_amdgcn_mfma_f32_16x16x16bf16_1k(a, b, c, 0, 0, 0);
#else
  asm volatile("v_mfma_f32_16x16x16_bf16 %0, %1, %2, %0" : "+v"(c) : "v"(a), "v"(b));
  return c;
#endif
}

// ---------------- Kernel 1: LSH hash ----------------
// spd transposed -> wave-uniform b128 broadcast reads. STAGING FIX (R9 bug):
// strided loop covers all 448 elements with 256 threads.
// Per-acc[r] FMA sequence identical to prior rounds (j ascending, x/y/z/w) —
// bit-identical hashes, no sign-flip risk.
__global__ __launch_bounds__(256) void hash_kernel(
    const float* __restrict__ q, const float* __restrict__ k,
    const float* __restrict__ pd, int* __restrict__ qh, int* __restrict__ kh) {
  __shared__ __align__(16) float spdT[R_][D_];   // [r][d]
  for (int i = threadIdx.x; i < D_ * R_; i += blockDim.x) {
    int d = i / R_, r = i - d * R_;              // pd[d*R + r]
    spdT[r][d] = pd[i];
  }
  __syncthreads();
  int tid = blockIdx.x * blockDim.x + threadIdx.x;
  const int half = BH_ * N_;
  const float* src = (tid < half) ? q : k;
  int* dst = (tid < half) ? qh : kh;
  int row = (tid < half) ? tid : tid - half;
  const float4* x4 = (const float4*)(src + (size_t)row * D_);
  float4 x[16];
#pragma unroll
  for (int j = 0; j < 16; j++) x[j] = x4[j];
  int bin = 0;
#pragma unroll
  for (int r = 0; r < R_; r++) {
    float a = 0.f;
#pragma unroll
    for (int j = 0; j < 16; j++) {
      float4 sp = *(const float4*)&spdT[r][4 * j];
      a = fmaf(x[j].x, sp.x, a);
      a = fmaf(x[j].y, sp.y, a);
      a = fmaf(x[j].z, sp.z, a);
      a = fmaf(x[j].w, sp.w, a);
    }
    bin |= (a > 0.f) ? (1 << r) : 0;
  }
  dst[row] = bin ^ (bin >> 1);
}

// ---------------- Kernel 2: stable counting sort, 256 threads/WG ----------------
// Each thread owns 32 consecutive positions. hist[bucket][thread] u16 (64 KiB).
// Two 1024-task parallel passes + one serial 128-prefix. Stability: thread
// order == position order; per-thread entries consecutive within a bucket.
__global__ __launch_bounds__(256) void sort_kernel(
    const int* __restrict__ qh, const int* __restrict__ kh,
    int* __restrict__ qidx, int* __restrict__ kidx) {
  int g = blockIdx.x;
  int bh = g & (BH_ - 1);
  bool isK = g >= BH_;
  const int* h = (isK ? kh : qh) + (size_t)bh * N_;
  int* idx = (isK ? kidx : qidx) + (size_t)bh * N_;
  __shared__ unsigned short hist[128][256];   // 64 KiB
  __shared__ int segsum[128][8];
  __shared__ int tot[128];
  __shared__ int off[128];
  const int t = threadIdx.x;

  {  // zero hist (u32x4 = 16 B stores)
    u32x4* hz = (u32x4*)hist;
    for (int i = t; i < 4096; i += 256) hz[i] = (u32x4){0u, 0u, 0u, 0u};
  }
  __syncthreads();

  const int base = t * 32;
  int hv[32];
#pragma unroll
  for (int j = 0; j < 32; j++) hv[j] = h[base + j];
#pragma unroll
  for (int j = 0; j < 32; j++) hist[hv[j]][t]++;
  __syncthreads();

  // seg sums: task = (bucket b, segment s of 32 thread-columns)
  for (int task = t; task < 1024; task += 256) {
    int b = task >> 3, s = task & 7;
    int sum = 0;
#pragma unroll
    for (int u = 0; u < 32; u++) sum += hist[b][s * 32 + u];
    segsum[b][s] = sum;
  }
  __syncthreads();

  if (t < 128) {  // per-bucket exclusive prefix over segments
    int run = 0;
#pragma unroll
    for (int s = 0; s < 8; s++) { int x = segsum[t][s]; segsum[t][s] = run; run += x; }
    tot[t] = run;
  }
  __syncthreads();

  if (t == 0) {   // global exclusive prefix over buckets
    int run = 0;
    for (int b = 0; b < 128; b++) { off[b] = run; run += tot[b]; }
  }
  __syncthreads();

  // convert hist[b][col] to global start offsets
  for (int task = t; task < 1024; task += 256) {
    int b = task >> 3, s = task & 7;
    int run = off[b] + segsum[b][s];
#pragma unroll
    for (int u = 0; u < 32; u++) {
      int x = hist[b][s * 32 + u];
      hist[b][s * 32 + u] = (unsigned short)run;
      run += x;
    }
  }
  __syncthreads();

  // stable scatter
#pragma unroll
  for (int j = 0; j < 32; j++) {
    int c = hv[j];
    int p = hist[c][t]++;
    idx[p] = base + j;
  }
}

// ---------------- Kernel 3: gather sampled K/V (256-thread blocks) ----------------
__global__ __launch_bounds__(256) void subgather_kernel(
    const float* __restrict__ key, const float* __restrict__ val,
    const int* __restrict__ kidx, const int* __restrict__ samp,
    float* __restrict__ ksub, float* __restrict__ vsub, int* __restrict__ sblk) {
  int sidx = blockIdx.x * 4 + (threadIdx.x >> 6);   // 0 .. BH*SAMPLE-1
  int bh = sidx >> 8;                                // SAMPLE_=256
  int d = threadIdx.x & 63;
  int pos = samp[sidx];
  int row = kidx[(size_t)bh * N_ + pos];
  ksub[(size_t)sidx * D_ + d] = key[((size_t)bh * N_ + row) * D_ + d];
  vsub[(size_t)sidx * D_ + d] = val[((size_t)bh * N_ + row) * D_ + d];
  if (d == 0) sblk[sidx] = pos >> 8;                 // BLOCK_=256
}

// ---------------- Kernel 4: MFMA fused attention (R6 structure — best measured) ----
__global__ __launch_bounds__(512, 4) void attn_kernel(
    const float* __restrict__ query, const float* __restrict__ key,
    const float* __restrict__ value,
    const int* __restrict__ qidx, const int* __restrict__ kidx,
    const float* __restrict__ ksub, const float* __restrict__ vsub,
    const int* __restrict__ sblk, float* __restrict__ out) {
  __shared__ __align__(16) unsigned short KsL[CHUNK_ * PADK];   // 18432 B
  __shared__ __align__(16) unsigned short VtL[D_ * PADV];       // 16896 B
  __shared__ int sbs[CHUNK_];
  __shared__ int qrows[BLOCK_];

  const int bh = blockIdx.x / NBLK_;
  const int blk = blockIdx.x - bh * NBLK_;
  const int tid = threadIdx.x;
  const int w = tid >> 6;       // wave 0..7
  const int lane = tid & 63;
  const int lg = lane >> 4;
  const int lr = lane & 15;
  const float FOLD = 0.18033688011112042f;   // (1/8) * log2(e)

  // ---- staging: thread -> (k-pair kp 0..63, d-octant dq 0..7) ----
  const int kp = tid >> 3, dq = tid & 7;
  auto stage_kv = [&](const float* kr0, const float* kr1,
                      const float* vr0, const float* vr1, int kbase) {
    float4 ka0 = *(const float4*)(kr0), ka1 = *(const float4*)(kr0 + 4);
    float4 kb0 = *(const float4*)(kr1), kb1 = *(const float4*)(kr1 + 4);
    u32x4 pk0 = (u32x4){pack2bf(ka0.x, ka0.y), pack2bf(ka0.z, ka0.w),
                        pack2bf(ka1.x, ka1.y), pack2bf(ka1.z, ka1.w)};
    u32x4 pk1 = (u32x4){pack2bf(kb0.x, kb0.y), pack2bf(kb0.z, kb0.w),
                        pack2bf(kb1.x, kb1.y), pack2bf(kb1.z, kb1.w)};
    *(u32x4*)&KsL[(kbase + 0) * PADK + dq * 8] = pk0;
    *(u32x4*)&KsL[(kbase + 1) * PADK + dq * 8] = pk1;
    float4 va0 = *(const float4*)(vr0), va1 = *(const float4*)(vr0 + 4);
    float4 vb0 = *(const float4*)(vr1), vb1 = *(const float4*)(vr1 + 4);
    float a[8] = {va0.x, va0.y, va0.z, va0.w, va1.x, va1.y, va1.z, va1.w};
    float b[8] = {vb0.x, vb0.y, vb0.z, vb0.w, vb1.x, vb1.y, vb1.z, vb1.w};
#pragma unroll
    for (int j = 0; j < 8; j++)
      *(unsigned*)&VtL[(dq * 8 + j) * PADV + kbase] = pack2bf(a[j], b[j]);
  };
  auto stage_block = [&](int c) {
    size_t ib = (size_t)bh * N_ + blk * BLOCK_ + c * CHUNK_ + 2 * kp;
    int r0 = kidx[ib], r1 = kidx[ib + 1];
    const float* k0 = key + ((size_t)bh * N_ + r0) * D_ + dq * 8;
    const float* k1 = key + ((size_t)bh * N_ + r1) * D_ + dq * 8;
    const float* v0 = value + ((size_t)bh * N_ + r0) * D_ + dq * 8;
    const float* v1 = value + ((size_t)bh * N_ + r1) * D_ + dq * 8;
    stage_kv(k0, k1, v0, v1, 2 * kp);
  };
  auto stage_sample = [&](int c) {
    size_t b0 = ((size_t)bh * SAMPLE_ + c * CHUNK_ + 2 * kp) * D_ + dq * 8;
    stage_kv(ksub + b0, ksub + b0 + D_, vsub + b0, vsub + b0 + D_, 2 * kp);
    if (tid < CHUNK_) sbs[tid] = sblk[(size_t)bh * SAMPLE_ + c * CHUNK_ + tid];
  };

  // ---- first chunk + qrows ----
  stage_block(0);
  if (tid < BLOCK_) qrows[tid] = qidx[(size_t)bh * N_ + blk * BLOCK_ + tid];
  __syncthreads();

  // ---- Q fragments (scale folded): lane holds Q[q=qt*16+lr][d=lg*8+h*32..+8] ----
  bf16x8 qf[2][2];
#pragma unroll
  for (int qt = 0; qt < 2; qt++) {
    int qrow = qrows[w * 32 + qt * 16 + lr];
    const float* qp = query + ((size_t)bh * N_ + qrow) * D_ + lg * 8;
#pragma unroll
    for (int h = 0; h < 2; h++) {
      float4 a = *(const float4*)(qp + h * 32);
      float4 b = *(const float4*)(qp + h * 32 + 4);
      union { u32x4 u; bf16x8 v; } cv;
      cv.u = (u32x4){pack2bf(a.x * FOLD, a.y * FOLD), pack2bf(a.z * FOLD, a.w * FOLD),
                     pack2bf(b.x * FOLD, b.y * FOLD), pack2bf(b.z * FOLD, b.w * FOLD)};
      qf[qt][h] = cv.v;
    }
  }

  // ---- ones A-fragment: A[row 0][*] = 1 -> D row 0 = column sums of W ----
  const bf16x4 avONE = (lr == 0)
      ? (bf16x4){(short)0x3F80, (short)0x3F80, (short)0x3F80, (short)0x3F80}
      : (bf16x4){0, 0, 0, 0};

  f32x4 oA[2][5], oB[2][5];   // [qt][dt]; dt==4 is the ls accumulator
#pragma unroll
  for (int a = 0; a < 2; a++)
#pragma unroll
    for (int b = 0; b < 5; b++) { oA[a][b] = (f32x4){0.f,0.f,0.f,0.f}; oB[a][b] = (f32x4){0.f,0.f,0.f,0.f}; }

  auto phase = [&](f32x4 (&o)[2][5], bool masked) {
#pragma unroll 1
    for (int kt = 0; kt < 8; kt++) {
      const unsigned short* krow = &KsL[(kt * 16 + lr) * PADK + lg * 8];
      bf16x8 ak0 = *(const bf16x8*)(krow);
      bf16x8 ak1 = *(const bf16x8*)(krow + 32);
      bf16x4 av[4];
#pragma unroll
      for (int dt = 0; dt < 4; dt++)
        av[dt] = *(const bf16x4*)(&VtL[(dt * 16 + lr) * PADV + kt * 16 + lg * 4]);
      float msk[4];
      if (masked) {
#pragma unroll
        for (int r = 0; r < 4; r++)
          msk[r] = (sbs[kt * 16 + lg * 4 + r] == blk) ? 0.f : 1.f;
      }
      bf16x4 bq[2];
#pragma unroll
      for (int qt = 0; qt < 2; qt++) {
        f32x4 c = (f32x4){0.f, 0.f, 0.f, 0.f};
        c = __builtin_amdgcn_mfma_f32_16x16x32_bf16(ak0, qf[qt][0], c, 0, 0, 0);
        c = __builtin_amdgcn_mfma_f32_16x16x32_bf16(ak1, qf[qt][1], c, 0, 0, 0);
        float w0 = fexp2(c[0]), w1 = fexp2(c[1]);
        float w2 = fexp2(c[2]), w3 = fexp2(c[3]);
        if (masked) { w0 *= msk[0]; w1 *= msk[1]; w2 *= msk[2]; w3 *= msk[3]; }
        union { u32x2 u; bf16x4 v; } cv;
        cv.u = (u32x2){pack2bf(w0, w1), pack2bf(w2, w3)};
        bq[qt] = cv.v;
      }
#pragma unroll
      for (int qt = 0; qt < 2; qt++) {
#pragma unroll
        for (int dt = 0; dt < 4; dt++)
          o[qt][dt] = mfma16(av[dt], bq[qt], o[qt][dt]);
        o[qt][4] = mfma16(avONE, bq[qt], o[qt][4]);
      }
    }
  };

  phase(oA, false);
  __syncthreads();
  stage_block(1);
  __syncthreads();
  phase(oA, false);
  __syncthreads();

  stage_sample(0);
  __syncthreads();
  phase(oB, true);
  __syncthreads();
  stage_sample(1);
  __syncthreads();
  phase(oB, true);

  // ---- merge + scatter (lane owns q = qt*16+lr, d = dt*16+lg*4..+4) ----
#pragma unroll
  for (int qt = 0; qt < 2; qt++) {
    float lb = __shfl(oA[qt][4][0], lr);     // lane (lr, lg=0) holds sum for q=lr
    float lrv = __shfl(oB[qt][4][0], lr);
    float wb, wr;
    float lseb = __logf(lb);
    if (lrv > 0.f) {
      float lser = __logf(lrv) + 3.4657359027997265f;  // + log(32)
      float cc = 1.f / (1.f + __expf(lser - lseb));
      wb = cc / lb; wr = (1.f - cc) / lrv;
    } else {
      wb = 1.f / lb; wr = 0.f;
    }
    int qr = qrows[w * 32 + qt * 16 + lr];
    float* op = out + ((size_t)bh * N_ + qr) * D_ + lg * 4;
#pragma unroll
    for (int dt = 0; dt < 4; dt++) {
      float4 o;
      o.x = wb * oA[qt][dt][0] + wr * oB[qt][dt][0];
      o.y = wb * oA[qt][dt][1] + wr * oB[qt][dt][1];
      o.z = wb * oA[qt][dt][2] + wr * oB[qt][dt][2];
      o.w = wb * oA[qt][dt][3] + wr * oB[qt][dt][3];
      *(float4*)(op + dt * 16) = o;
    }
  }
}

extern "C" void kernel_launch(void* const* d_in, const int* in_sizes, int n_in,
                              void* d_out, int out_size, void* d_ws, size_t ws_size,
                              hipStream_t stream) {
  const float* query = (const float*)d_in[0];
  const float* key   = (const float*)d_in[1];
  const float* value = (const float*)d_in[2];
  const float* pd    = (const float*)d_in[3];
  const int*   samp  = (const int*)d_in[4];
  float* out = (float*)d_out;

  char* w = (char*)d_ws;
  size_t o = 0;
  auto alloc = [&](size_t bytes) { void* p = w + o; o = (o + bytes + 255) & ~(size_t)255; return p; };
  int* qh   = (int*)alloc((size_t)BH_ * N_ * 4);
  int* kh   = (int*)alloc((size_t)BH_ * N_ * 4);
  int* qidx = (int*)alloc((size_t)BH_ * N_ * 4);
  int* kidx = (int*)alloc((size_t)BH_ * N_ * 4);
  float* ksub = (float*)alloc((size_t)BH_ * SAMPLE_ * D_ * 4);
  float* vsub = (float*)alloc((size_t)BH_ * SAMPLE_ * D_ * 4);
  int* sblk = (int*)alloc((size_t)BH_ * SAMPLE_ * 4);

  hash_kernel<<<(2 * BH_ * N_) / 256, 256, 0, stream>>>(query, key, pd, qh, kh);
  sort_kernel<<<2 * BH_, 256, 0, stream>>>(qh, kh, qidx, kidx);
  subgather_kernel<<<BH_ * SAMPLE_ / 4, 256, 0, stream>>>(key, value, kidx, samp, ksub, vsub, sblk);
  attn_kernel<<<BH_ * NBLK_, 512, 0, stream>>>(query, key, value, qidx, kidx,
                                               ksub, vsub, sblk, out);
}